// Round 7
// baseline (498.490 us; speedup 1.0000x reference)
//
#include <hip/hip_runtime.h>
#include <hip/hip_bf16.h>
#include <stdint.h>

typedef unsigned short u16;
typedef __bf16 bf16x8 __attribute__((ext_vector_type(8)));
typedef float f32x4 __attribute__((ext_vector_type(4)));
typedef float f32x8 __attribute__((ext_vector_type(8)));

#define BM 128
#define BN 128
#define BK 64

struct SegArgs {
  const u16* W[4];
  const float* b[4];
  void* out[4];
  int act[4];      // 0=none 1=sigmoid 2=tanh 3=relu
  int bf16out[4];  // 1 = store bf16, 0 = store fp32
};

// fused LSTM-gate GEMM args
struct LstmArgs {
  const u16* W[4];     // Wf, Wi, Wc, Wo  [1024 x K] bf16 row-major
  const float* b[4];   // biases
  const float* cold;   // c_in  [4096 x 1024] fp32
  float* h;            // h_out [4096 x 1024] fp32
  float* c;            // c_out [4096 x 1024] fp32
  u16*   hb;           // h_out bf16 (next GEMM's A-side)
};

// interleaved fp32->bf16 conversion work (regions of 2M fp32 each).
// Each block owns a contiguous 2048-group (16K-elem) slice; 64 groups are
// converted per K-step inside the MFMA phase's latency shadow.
struct CvtW { const float* src[8]; u16* dst[8]; int n; };

__device__ __forceinline__ float bf2f(u16 u) {
  union { unsigned int i; float f; } v; v.i = ((unsigned int)u) << 16; return v.f;
}
__device__ __forceinline__ u16 f2bf(float f) {
  union { float f; unsigned int i; } v; v.f = f;
  return (u16)((v.i + 0x7fffu + ((v.i >> 16) & 1u)) >> 16);
}
__device__ __forceinline__ uint4 cvt8(f32x8 v) {
  uint4 r;
  r.x = (unsigned)f2bf(v[0]) | ((unsigned)f2bf(v[1]) << 16);
  r.y = (unsigned)f2bf(v[2]) | ((unsigned)f2bf(v[3]) << 16);
  r.z = (unsigned)f2bf(v[4]) | ((unsigned)f2bf(v[5]) << 16);
  r.w = (unsigned)f2bf(v[6]) | ((unsigned)f2bf(v[7]) << 16);
  return r;
}
__device__ __forceinline__ float actf(float x, int act) {
  if (act == 1) return 1.0f / (1.0f + __expf(-x));
  if (act == 2) {
    float xc = fminf(fmaxf(x, -15.0f), 15.0f);
    float e = __expf(2.0f * xc);
    return (e - 1.0f) / (e + 1.0f);
  }
  if (act == 3) return fmaxf(x, 0.0f);
  return x;
}

// ---- bulk fp32 -> bf16 convert; chunk = 2M elements, blockIdx.y = chunk ----
struct CvtArgs { const float* src[10]; u16* dst[10]; };
__global__ void cvt_f2b(CvtArgs a) {
  const float* s = a.src[blockIdx.y];
  u16* d = a.dst[blockIdx.y];
  int i0 = (blockIdx.x * 256 + threadIdx.x) * 8;
  f32x8 v = *(const f32x8*)(s + i0);
  *(uint4*)(d + i0) = cvt8(v);
}

// ============================================================================
// gemm_lstm2: m97-structure 128x128 GEMM, virtual N = 4 gates seg-blocked
// (staging iteration it == gate).  Fused LSTM epilogue (round-4 verified):
// wave-uniform activation -> LDS bf16 exchange -> coalesced h/c/hb writes.
// Round 7: TEMPORALLY INTERLEAVED cvt — per K-step, wave 0 loads 64x32B of
// next-phase fp32 right AFTER the staging barrier (so the staging drain does
// not wait on it), the ~900cy HBM latency hides under the ~1200cy MFMA
// phase, and the bf16 store issues just before the closing barrier.
// (Round-6 lesson: a batched prologue serializes the same BW work at kernel
// start, +27us; spatial distribution without temporal interleave hides
// nothing.)  Region index is block-uniform (128 blocks/region exactly), so
// src/dst collapse to two pointers advanced 512 elems/step.
// ============================================================================
__global__ __launch_bounds__(256, 2) void gemm_lstm2(
    const u16* __restrict__ A0, const u16* __restrict__ A1, int KA0, int K,
    LstmArgs La, CvtW cw)
{
  __shared__ u16 smem[2 * 8192];         // As = smem, Bs = smem + 8192
  u16* As = smem;
  u16* Bs = smem + 8192;

  const int tid  = threadIdx.x;
  const int lane = tid & 63;
  const int wave = tid >> 6;
  const int mBlock = blockIdx.x * BM;
  const int nTile  = blockIdx.y;              // 32 real cols per tile
  const int colBase32 = nTile * 32;
  const int wm = wave & 1, wn = wave >> 1;

  // ---- interleaved-cvt setup (wave 0 only; region is block-uniform) ----
  const int gps = cw.n << 3;                  // groups per K-step (K/BK = 32)
  const float* cvtS = nullptr;
  u16* cvtD = nullptr;
  if (cw.n && tid < gps) {
    const int bid = blockIdx.y * gridDim.x + blockIdx.x;   // 0..1023
    const int region = bid >> 7;              // 128 blocks per 2M-elem region
    const size_t off = ((size_t)(bid & 127) * 2048 + tid) * 8;
    cvtS = cw.src[region] + off;
    cvtD = cw.dst[region] + off;
  }
  const size_t cvtStep = (size_t)gps * 8;     // elems advanced per K-step

  // staging: slot s = it*256+tid, virtual row m = s>>3 = it*32 + (tid>>3),
  // XOR-swizzled chunk kc = (tid&7) ^ ((tid>>3)&7)  (constant across it).
  const int rsub = tid >> 3;
  const int kc   = (tid & 7) ^ (rsub & 7);
  const u16* pA[4];
  const u16* pB[4];
#pragma unroll
  for (int it = 0; it < 4; ++it) {
    pB[it] = La.W[it] + (size_t)(colBase32 + rsub) * (size_t)K + kc * 8;
    pA[it] = A0 + (size_t)(mBlock + it * 32 + rsub) * (size_t)KA0 + kc * 8;
  }

  const f32x4 zero = {0.f, 0.f, 0.f, 0.f};
  f32x4 acc[4][4];
#pragma unroll
  for (int i = 0; i < 4; ++i)
#pragma unroll
    for (int j = 0; j < 4; ++j) acc[i][j] = zero;

  for (int kb = 0; kb < K; kb += BK) {
    if (kb == KA0) {   // A-side segment switch (concat(x,h) unmaterialized)
#pragma unroll
      for (int it = 0; it < 4; ++it)
        pA[it] = A1 + (size_t)(mBlock + it * 32 + rsub) * (size_t)(K - KA0) + kc * 8;
    }
#pragma unroll
    for (int it = 0; it < 4; ++it) {
      u16* dA = &As[(it * 256 + wave * 64) * 8];
      u16* dB = &Bs[(it * 256 + wave * 64) * 8];
      __builtin_amdgcn_global_load_lds((void*)pA[it], (void*)dA, 16, 0, 0);
      __builtin_amdgcn_global_load_lds((void*)pB[it], (void*)dB, 16, 0, 0);
      pA[it] += BK; pB[it] += BK;
    }
    __syncthreads();

    // issue this step's cvt load AFTER the staging drain; it completes
    // under the MFMA phase and is consumed just before the closing barrier.
    f32x8 cvtv;
    if (cvtD) cvtv = *(const f32x8*)cvtS;

#pragma unroll
    for (int ko = 0; ko < 2; ++ko) {
      bf16x8 af[4], bfr[4];
      int kcb = ko * 4 + (lane >> 4);
      int p = kcb ^ (lane & 7);
#pragma unroll
      for (int t = 0; t < 4; ++t) {
        int ml = wm * 64 + t * 16 + (lane & 15);
        af[t]  = *(const bf16x8*)&As[(ml * 8 + p) * 8];
        int nl = wn * 64 + t * 16 + (lane & 15);
        bfr[t] = *(const bf16x8*)&Bs[(nl * 8 + p) * 8];
      }
#pragma unroll
      for (int tm = 0; tm < 4; ++tm)
#pragma unroll
        for (int tn = 0; tn < 4; ++tn)
          acc[tm][tn] = __builtin_amdgcn_mfma_f32_16x16x32_bf16(af[tm], bfr[tn], acc[tm][tn], 0, 0, 0);
    }

    if (cvtD) {
      *(uint4*)cvtD = cvt8(cvtv);
      cvtS += cvtStep;
      cvtD += cvtStep;
    }
    __syncthreads();
  }

  // ---- epilogue stage 1: bias + activation -> LDS gate buffer (bf16) ----
  const int cl = lane & 15;
  const int q4 = (lane >> 4) * 4;
#pragma unroll
  for (int tn = 0; tn < 4; ++tn) {
    const int g = wn * 2 + (tn >> 1);
    const float* bg = (tn >> 1) ? (wn ? La.b[3] : La.b[1])
                                : (wn ? La.b[2] : La.b[0]);
    const bool isT = (wn == 1) && ((tn >> 1) == 0);   // gate 2 = cand -> tanh
    const int col = (tn & 1) * 16 + cl;
    float bv = bg[colBase32 + col];
#pragma unroll
    for (int tm = 0; tm < 4; ++tm) {
      const int rbase = wm * 64 + tm * 16 + q4;
#pragma unroll
      for (int r = 0; r < 4; ++r) {
        float x = acc[tm][tn][r] + bv;
        float a;
        if (isT) {
          float xc = fminf(fmaxf(x, -15.f), 15.f);
          float e = __expf(2.f * xc);
          a = (e - 1.f) / (e + 1.f);
        } else {
          a = 1.f / (1.f + __expf(-x));
        }
        int row = rbase + r;
        smem[g * 4096 + row * 32 + (((col >> 3) ^ ((row >> 2) & 3)) << 3) + (col & 7)] = f2bf(a);
      }
    }
  }
  __syncthreads();

  // ---- epilogue stage 2: combine, coalesced global I/O ----
  {
    const int rowL = tid >> 1;
    const int hf   = tid & 1;
    const int xr   = (rowL >> 2) & 3;
    union GU { uint4 v; u16 u[8]; };
    GU gu[4][2];
#pragma unroll
    for (int g = 0; g < 4; ++g)
#pragma unroll
      for (int jj = 0; jj < 2; ++jj) {
        int ch = (hf * 2 + jj) ^ xr;
        gu[g][jj].v = *(const uint4*)&smem[g * 4096 + rowL * 32 + ch * 8];
      }
    size_t base = (size_t)(mBlock + rowL) * 1024 + colBase32 + hf * 16;
    f32x8 cA = *(const f32x8*)(La.cold + base);
    f32x8 cB = *(const f32x8*)(La.cold + base + 8);
    f32x8 H0, H1, C0, C1;
#pragma unroll
    for (int j = 0; j < 8; ++j) {
      float f  = bf2f(gu[0][0].u[j]);
      float iv = bf2f(gu[1][0].u[j]);
      float cd = bf2f(gu[2][0].u[j]);
      float o  = bf2f(gu[3][0].u[j]);
      float cn = f * cA[j] + cd * iv;
      float e  = __expf(2.0f * cd);
      float th = (e - 1.0f) / (e + 1.0f);
      H0[j] = o * th;                  // faithful double-tanh
      C0[j] = cn;
    }
#pragma unroll
    for (int j = 0; j < 8; ++j) {
      float f  = bf2f(gu[0][1].u[j]);
      float iv = bf2f(gu[1][1].u[j]);
      float cd = bf2f(gu[2][1].u[j]);
      float o  = bf2f(gu[3][1].u[j]);
      float cn = f * cB[j] + cd * iv;
      float e  = __expf(2.0f * cd);
      float th = (e - 1.0f) / (e + 1.0f);
      H1[j] = o * th;
      C1[j] = cn;
    }
    *(f32x8*)(La.h + base)     = H0;
    *(f32x8*)(La.h + base + 8) = H1;
    *(f32x8*)(La.c + base)     = C0;
    *(f32x8*)(La.c + base + 8) = C1;
    *(uint4*)(La.hb + base)     = cvt8(H0);
    *(uint4*)(La.hb + base + 8) = cvt8(H1);
  }
}

// ---- 128x128 m97-structure kernel (unchanged, round-0 verified): heads ----
__global__ __launch_bounds__(256, 2) void gemm_bt(
    const u16* __restrict__ A0, const u16* __restrict__ A1, int KA0, int K,
    SegArgs segs, int tileShift, int ldOut)
{
  __shared__ u16 As[BM * BK];
  __shared__ u16 Bs[BN * BK];

  const int tid  = threadIdx.x;
  const int lane = tid & 63;
  const int wave = tid >> 6;
  const int mBlock = blockIdx.x * BM;
  const int seg   = blockIdx.y >> tileShift;
  const int nTile = blockIdx.y & ((1 << tileShift) - 1);

  const u16* Wp = segs.W[seg];
  const int wm = wave & 1, wn = wave >> 1;

  const f32x4 zero = {0.f, 0.f, 0.f, 0.f};
  f32x4 acc[4][4];
#pragma unroll
  for (int i = 0; i < 4; ++i)
#pragma unroll
    for (int j = 0; j < 4; ++j) acc[i][j] = zero;

  for (int kb = 0; kb < K; kb += BK) {
    const u16* Aseg; int ka; int ldA;
    if (kb < KA0) { Aseg = A0; ka = kb;       ldA = KA0; }
    else          { Aseg = A1; ka = kb - KA0; ldA = K - KA0; }

#pragma unroll
    for (int it = 0; it < 4; ++it) {
      int s = it * 256 + tid;
      int m = s >> 3;
      int p = s & 7;
      int kc = p ^ (m & 7);
      const u16* srcA = Aseg + (size_t)(mBlock + m) * (size_t)ldA + (ka + kc * 8);
      const u16* srcB = Wp + (size_t)(nTile * BN + m) * (size_t)K + (kb + kc * 8);
      u16* dA = &As[(it * 256 + wave * 64) * 8];
      u16* dB = &Bs[(it * 256 + wave * 64) * 8];
      __builtin_amdgcn_global_load_lds((void*)srcA, (void*)dA, 16, 0, 0);
      __builtin_amdgcn_global_load_lds((void*)srcB, (void*)dB, 16, 0, 0);
    }
    __syncthreads();

#pragma unroll
    for (int ko = 0; ko < 2; ++ko) {
      bf16x8 af[4], bfr[4];
      int kcb = ko * 4 + (lane >> 4);
      int p = kcb ^ (lane & 7);
#pragma unroll
      for (int t = 0; t < 4; ++t) {
        int ml = wm * 64 + t * 16 + (lane & 15);
        af[t]  = *(const bf16x8*)&As[(ml * 8 + p) * 8];
        int nl = wn * 64 + t * 16 + (lane & 15);
        bfr[t] = *(const bf16x8*)&Bs[(nl * 8 + p) * 8];
      }
#pragma unroll
      for (int tm = 0; tm < 4; ++tm)
#pragma unroll
        for (int tn = 0; tn < 4; ++tn)
          acc[tm][tn] = __builtin_amdgcn_mfma_f32_16x16x32_bf16(af[tm], bfr[tn], acc[tm][tn], 0, 0, 0);
    }
    __syncthreads();
  }

  const float* bp = segs.b[seg];
  const int act = segs.act[seg];
  const int isBf = segs.bf16out[seg];
  u16*   opb = (u16*)segs.out[seg];
  float* opf = (float*)segs.out[seg];
  const int q  = lane >> 4;
  const int cl = lane & 15;
#pragma unroll
  for (int tn = 0; tn < 4; ++tn) {
    int col = nTile * BN + wn * 64 + tn * 16 + cl;
    float bv = bp[col];
#pragma unroll
    for (int tm = 0; tm < 4; ++tm) {
      int row = mBlock + wm * 64 + tm * 16 + q * 4;
#pragma unroll
      for (int r = 0; r < 4; ++r) {
        float v = actf(acc[tm][tn][r] + bv, act);
        size_t idx = (size_t)(row + r) * (size_t)ldOut + col;
        if (isBf) opb[idx] = f2bf(v); else opf[idx] = v;
      }
    }
  }
}

extern "C" void kernel_launch(void* const* d_in, const int* in_sizes, int n_in,
                              void* d_out, int out_size, void* d_ws, size_t ws_size,
                              hipStream_t stream)
{
  const size_t P   = 4096ull * 1024ull;  // 4,194,304 elements
  const size_t C2M = 2097152ull;         // region = 2M elements

  const float* X   = (const float*)d_in[0];
  const float* h1i = (const float*)d_in[1];
  const float* h2i = (const float*)d_in[2];
  const float* c1i = (const float*)d_in[3];
  const float* c2i = (const float*)d_in[4];
  const float* Wf1 = (const float*)d_in[5];  const float* bf1_ = (const float*)d_in[6];
  const float* Wi1 = (const float*)d_in[7];  const float* bi1_ = (const float*)d_in[8];
  const float* Wc1 = (const float*)d_in[9];  const float* bc1_ = (const float*)d_in[10];
  const float* Wo1 = (const float*)d_in[11]; const float* bo1_ = (const float*)d_in[12];
  const float* Wf2 = (const float*)d_in[13]; const float* bf2_ = (const float*)d_in[14];
  const float* Wi2 = (const float*)d_in[15]; const float* bi2_ = (const float*)d_in[16];
  const float* Wc2 = (const float*)d_in[17]; const float* bc2_ = (const float*)d_in[18];
  const float* Wo2 = (const float*)d_in[19]; const float* bo2_ = (const float*)d_in[20];
  const float* W3  = (const float*)d_in[21]; const float* b3_  = (const float*)d_in[22];
  const float* W4  = (const float*)d_in[23]; const float* b4_  = (const float*)d_in[24];

  float* out = (float*)d_out;     // fp32 outputs (reference dtype)
  float* h1  = out + P;
  float* h2  = out + 2 * P;
  float* c1  = out + 3 * P;
  float* c2  = out + 4 * P;

  // ws layout (80 MB), non-aliased during layer 1 (interleaved cvt targets):
  //  W1b  @  0MB (16)      W2b  @ 16MB (16)
  //  W3b  @ 32MB ( 4)      W4b  @ 36MB ( 4)
  //  Xb   @ 40MB ( 8)      h1ib @ 48MB ( 8)
  //  h2ib @ 56MB ( 8)
  //  h1b  @ 64MB ( 8)      h2b  @ 72MB ( 8)
  //  out3b@  0MB (16)      (reuses W1b region, dead after gemm1)
  char* ws = (char*)d_ws;
  u16* W1b  = (u16*)ws;
  u16* W2b  = (u16*)(ws + (16ull << 20));
  u16* W3b  = (u16*)(ws + (32ull << 20));
  u16* W4b  = (u16*)(ws + (36ull << 20));
  u16* Xb   = (u16*)(ws + (40ull << 20));
  u16* h1ib = (u16*)(ws + (48ull << 20));
  u16* h2ib = (u16*)(ws + (56ull << 20));
  u16* h1b  = (u16*)(ws + (64ull << 20));
  u16* h2b  = (u16*)(ws + (72ull << 20));
  u16* out3b = W1b;

  dim3 blk(256, 1, 1);

  // ---- cvtA: only gemm1's direct inputs (W1 gates, X, h1i) ----
  CvtArgs ca;
  ca.src[0]=Wf1;        ca.dst[0]=W1b;
  ca.src[1]=Wi1;        ca.dst[1]=W1b + C2M;
  ca.src[2]=Wc1;        ca.dst[2]=W1b + 2*C2M;
  ca.src[3]=Wo1;        ca.dst[3]=W1b + 3*C2M;
  ca.src[4]=X;          ca.dst[4]=Xb;
  ca.src[5]=X + C2M;    ca.dst[5]=Xb + C2M;
  ca.src[6]=h1i;        ca.dst[6]=h1ib;
  ca.src[7]=h1i + C2M;  ca.dst[7]=h1ib + C2M;
  ca.src[8]=nullptr;    ca.dst[8]=nullptr;
  ca.src[9]=nullptr;    ca.dst[9]=nullptr;
  cvt_f2b<<<dim3(1024, 8, 1), blk, 0, stream>>>(ca);

  // ---- LSTM layer 1 + interleaved cvt (W2 gates, h2i, W3, W4) ----
  LstmArgs l1;
  l1.W[0]=W1b; l1.W[1]=W1b+C2M; l1.W[2]=W1b+2*C2M; l1.W[3]=W1b+3*C2M;
  l1.b[0]=bf1_; l1.b[1]=bi1_; l1.b[2]=bc1_; l1.b[3]=bo1_;
  l1.cold=c1i; l1.h=h1; l1.c=c1; l1.hb=h1b;
  CvtW cw1;
  cw1.src[0]=Wf2;       cw1.dst[0]=W2b;
  cw1.src[1]=Wi2;       cw1.dst[1]=W2b + C2M;
  cw1.src[2]=Wc2;       cw1.dst[2]=W2b + 2*C2M;
  cw1.src[3]=Wo2;       cw1.dst[3]=W2b + 3*C2M;
  cw1.src[4]=h2i;       cw1.dst[4]=h2ib;
  cw1.src[5]=h2i + C2M; cw1.dst[5]=h2ib + C2M;
  cw1.src[6]=W3;        cw1.dst[6]=W3b;
  cw1.src[7]=W4;        cw1.dst[7]=W4b;
  cw1.n = 8;
  gemm_lstm2<<<dim3(32, 32, 1), blk, 0, stream>>>(Xb, h1ib, 1024, 2048, l1, cw1);

  // ---- LSTM layer 2: A = [h1b | h2ib] ----
  LstmArgs l2;
  l2.W[0]=W2b; l2.W[1]=W2b+C2M; l2.W[2]=W2b+2*C2M; l2.W[3]=W2b+3*C2M;
  l2.b[0]=bf2_; l2.b[1]=bi2_; l2.b[2]=bc2_; l2.b[3]=bo2_;
  l2.cold=c2i; l2.h=h2; l2.c=c2; l2.hb=h2b;
  CvtW cw0; cw0.n = 0;
  for (int i = 0; i < 8; ++i) { cw0.src[i]=nullptr; cw0.dst[i]=nullptr; }
  gemm_lstm2<<<dim3(32, 32, 1), blk, 0, stream>>>(h1b, h2ib, 1024, 2048, l2, cw0);

  // ---- head: out3b = relu(h2b @ W3^T + b3), N=2048, K=1024, bf16 out ----
  SegArgs s3;
  for (int g = 0; g < 4; ++g) { s3.W[g]=W3b; s3.b[g]=b3_; s3.out[g]=out3b; s3.act[g]=3; s3.bf16out[g]=1; }
  gemm_bt<<<dim3(32,16,1), blk, 0, stream>>>(h2b, (const u16*)nullptr, 1024, 1024, s3, 4, 2048);

  // ---- head: out = out3b @ W4^T + b4, N=1024, K=2048, fp32 out ----
  SegArgs s4;
  for (int g = 0; g < 4; ++g) { s4.W[g]=W4b; s4.b[g]=b4_; s4.out[g]=out; s4.act[g]=0; s4.bf16out[g]=0; }
  gemm_bt<<<dim3(32,8,1), blk, 0, stream>>>(out3b, (const u16*)nullptr, 2048, 2048, s4, 3, 1024);
}

// Round 8
// 466.169 us; speedup vs baseline: 1.0693x; 1.0693x over previous
//
#include <hip/hip_runtime.h>
#include <hip/hip_bf16.h>
#include <stdint.h>

typedef unsigned short u16;
typedef __bf16 bf16x8 __attribute__((ext_vector_type(8)));
typedef float f32x4 __attribute__((ext_vector_type(4)));
typedef float f32x8 __attribute__((ext_vector_type(8)));

#define BM 128
#define BN 128
#define BK 64

struct SegArgs {
  const u16* W[4];
  const float* b[4];
  void* out[4];
  int act[4];      // 0=none 1=sigmoid 2=tanh 3=relu
  int bf16out[4];  // 1 = store bf16, 0 = store fp32
};

// fused LSTM-gate GEMM args
struct LstmArgs {
  const u16* W[4];     // Wf, Wi, Wc, Wo  [1024 x K] bf16 row-major
  const float* b[4];   // biases
  const float* cold;   // c_in  [4096 x 1024] fp32
  float* h;            // h_out [4096 x 1024] fp32
  float* c;            // c_out [4096 x 1024] fp32
  u16*   hb;           // h_out bf16 (next GEMM's A-side)
};

// staggered fp32->bf16 conversion work (regions of 2M fp32 each).
// Only blocks bid >= 512 (the SECOND scheduling wave) convert a 4096-group
// slice before their GEMM: their prologue overlaps the first wave's MFMA
// phase on the same CUs instead of forming a serialized BW phase at t=0
// (round-6 lesson) and never touches the K-loop (round-7 lesson).
struct CvtW { const float* src[8]; u16* dst[8]; int n; };

__device__ __forceinline__ float bf2f(u16 u) {
  union { unsigned int i; float f; } v; v.i = ((unsigned int)u) << 16; return v.f;
}
__device__ __forceinline__ u16 f2bf(float f) {
  union { float f; unsigned int i; } v; v.f = f;
  return (u16)((v.i + 0x7fffu + ((v.i >> 16) & 1u)) >> 16);
}
__device__ __forceinline__ uint4 cvt8(f32x8 v) {
  uint4 r;
  r.x = (unsigned)f2bf(v[0]) | ((unsigned)f2bf(v[1]) << 16);
  r.y = (unsigned)f2bf(v[2]) | ((unsigned)f2bf(v[3]) << 16);
  r.z = (unsigned)f2bf(v[4]) | ((unsigned)f2bf(v[5]) << 16);
  r.w = (unsigned)f2bf(v[6]) | ((unsigned)f2bf(v[7]) << 16);
  return r;
}
__device__ __forceinline__ float actf(float x, int act) {
  if (act == 1) return 1.0f / (1.0f + __expf(-x));
  if (act == 2) {
    float xc = fminf(fmaxf(x, -15.0f), 15.0f);
    float e = __expf(2.0f * xc);
    return (e - 1.0f) / (e + 1.0f);
  }
  if (act == 3) return fmaxf(x, 0.0f);
  return x;
}

// ---- bulk fp32 -> bf16 convert; chunk = 2M elements, blockIdx.y = chunk ----
struct CvtArgs { const float* src[10]; u16* dst[10]; };
__global__ void cvt_f2b(CvtArgs a) {
  const float* s = a.src[blockIdx.y];
  u16* d = a.dst[blockIdx.y];
  int i0 = (blockIdx.x * 256 + threadIdx.x) * 8;
  f32x8 v = *(const f32x8*)(s + i0);
  *(uint4*)(d + i0) = cvt8(v);
}

// ============================================================================
// gemm_lstm2: m97-structure 128x128 GEMM, virtual N = 4 gates seg-blocked
// (staging iteration it == gate).  Fused LSTM epilogue (round-4 verified):
// wave-uniform activation -> LDS bf16 exchange -> coalesced h/c/hb writes.
// Round 8: STAGGERED cvt prologue — only the second block-wave (bid >= 512)
// converts next-phase fp32->bf16, overlapping the first wave's GEMM compute.
// K-loop is the clean round-0-verified form (no global ops inside: round 7
// showed any rider op inside the barrier-locked loop costs ~1500cy/step).
// ============================================================================
__global__ __launch_bounds__(256, 2) void gemm_lstm2(
    const u16* __restrict__ A0, const u16* __restrict__ A1, int KA0, int K,
    LstmArgs La, CvtW cw)
{
  __shared__ u16 smem[2 * 8192];         // As = smem, Bs = smem + 8192
  u16* As = smem;
  u16* Bs = smem + 8192;

  const int tid  = threadIdx.x;

  // ---- staggered conversion prologue: second block-wave only ----
  if (cw.n) {
    const int bid = blockIdx.y * gridDim.x + blockIdx.x;   // 0..1023
    if (bid >= 512) {
      const int sb = bid - 512;                 // 0..511
      const int region = sb >> 6;               // 64 blocks per 2M-elem region
      const float* s0 = cw.src[region];
      u16* d0 = cw.dst[region];
      const size_t off0 = (size_t)(sb & 63) * 4096 * 8;
#pragma unroll 2
      for (int i = 0; i < 4096; i += 256) {
        size_t off = off0 + (size_t)(i + tid) * 8;
        f32x8 v = *(const f32x8*)(s0 + off);
        *(uint4*)(d0 + off) = cvt8(v);
      }
    }
  }

  const int lane = tid & 63;
  const int wave = tid >> 6;
  const int mBlock = blockIdx.x * BM;
  const int nTile  = blockIdx.y;              // 32 real cols per tile
  const int colBase32 = nTile * 32;
  const int wm = wave & 1, wn = wave >> 1;

  // staging: slot s = it*256+tid, virtual row m = s>>3 = it*32 + (tid>>3),
  // XOR-swizzled chunk kc = (tid&7) ^ ((tid>>3)&7)  (constant across it).
  const int rsub = tid >> 3;
  const int kc   = (tid & 7) ^ (rsub & 7);
  const u16* pA[4];
  const u16* pB[4];
#pragma unroll
  for (int it = 0; it < 4; ++it) {
    pB[it] = La.W[it] + (size_t)(colBase32 + rsub) * (size_t)K + kc * 8;
    pA[it] = A0 + (size_t)(mBlock + it * 32 + rsub) * (size_t)KA0 + kc * 8;
  }

  const f32x4 zero = {0.f, 0.f, 0.f, 0.f};
  f32x4 acc[4][4];
#pragma unroll
  for (int i = 0; i < 4; ++i)
#pragma unroll
    for (int j = 0; j < 4; ++j) acc[i][j] = zero;

  for (int kb = 0; kb < K; kb += BK) {
    if (kb == KA0) {   // A-side segment switch (concat(x,h) unmaterialized)
#pragma unroll
      for (int it = 0; it < 4; ++it)
        pA[it] = A1 + (size_t)(mBlock + it * 32 + rsub) * (size_t)(K - KA0) + kc * 8;
    }
#pragma unroll
    for (int it = 0; it < 4; ++it) {
      u16* dA = &As[(it * 256 + wave * 64) * 8];
      u16* dB = &Bs[(it * 256 + wave * 64) * 8];
      __builtin_amdgcn_global_load_lds((void*)pA[it], (void*)dA, 16, 0, 0);
      __builtin_amdgcn_global_load_lds((void*)pB[it], (void*)dB, 16, 0, 0);
      pA[it] += BK; pB[it] += BK;
    }
    __syncthreads();

#pragma unroll
    for (int ko = 0; ko < 2; ++ko) {
      bf16x8 af[4], bfr[4];
      int kcb = ko * 4 + (lane >> 4);
      int p = kcb ^ (lane & 7);
#pragma unroll
      for (int t = 0; t < 4; ++t) {
        int ml = wm * 64 + t * 16 + (lane & 15);
        af[t]  = *(const bf16x8*)&As[(ml * 8 + p) * 8];
        int nl = wn * 64 + t * 16 + (lane & 15);
        bfr[t] = *(const bf16x8*)&Bs[(nl * 8 + p) * 8];
      }
#pragma unroll
      for (int tm = 0; tm < 4; ++tm)
#pragma unroll
        for (int tn = 0; tn < 4; ++tn)
          acc[tm][tn] = __builtin_amdgcn_mfma_f32_16x16x32_bf16(af[tm], bfr[tn], acc[tm][tn], 0, 0, 0);
    }
    __syncthreads();
  }

  // ---- epilogue stage 1: bias + activation -> LDS gate buffer (bf16) ----
  const int cl = lane & 15;
  const int q4 = (lane >> 4) * 4;
#pragma unroll
  for (int tn = 0; tn < 4; ++tn) {
    const int g = wn * 2 + (tn >> 1);
    const float* bg = (tn >> 1) ? (wn ? La.b[3] : La.b[1])
                                : (wn ? La.b[2] : La.b[0]);
    const bool isT = (wn == 1) && ((tn >> 1) == 0);   // gate 2 = cand -> tanh
    const int col = (tn & 1) * 16 + cl;
    float bv = bg[colBase32 + col];
#pragma unroll
    for (int tm = 0; tm < 4; ++tm) {
      const int rbase = wm * 64 + tm * 16 + q4;
#pragma unroll
      for (int r = 0; r < 4; ++r) {
        float x = acc[tm][tn][r] + bv;
        float a;
        if (isT) {
          float xc = fminf(fmaxf(x, -15.f), 15.f);
          float e = __expf(2.f * xc);
          a = (e - 1.f) / (e + 1.f);
        } else {
          a = 1.f / (1.f + __expf(-x));
        }
        int row = rbase + r;
        smem[g * 4096 + row * 32 + (((col >> 3) ^ ((row >> 2) & 3)) << 3) + (col & 7)] = f2bf(a);
      }
    }
  }
  __syncthreads();

  // ---- epilogue stage 2: combine, coalesced global I/O ----
  {
    const int rowL = tid >> 1;
    const int hf   = tid & 1;
    const int xr   = (rowL >> 2) & 3;
    union GU { uint4 v; u16 u[8]; };
    GU gu[4][2];
#pragma unroll
    for (int g = 0; g < 4; ++g)
#pragma unroll
      for (int jj = 0; jj < 2; ++jj) {
        int ch = (hf * 2 + jj) ^ xr;
        gu[g][jj].v = *(const uint4*)&smem[g * 4096 + rowL * 32 + ch * 8];
      }
    size_t base = (size_t)(mBlock + rowL) * 1024 + colBase32 + hf * 16;
    f32x8 cA = *(const f32x8*)(La.cold + base);
    f32x8 cB = *(const f32x8*)(La.cold + base + 8);
    f32x8 H0, H1, C0, C1;
#pragma unroll
    for (int j = 0; j < 8; ++j) {
      float f  = bf2f(gu[0][0].u[j]);
      float iv = bf2f(gu[1][0].u[j]);
      float cd = bf2f(gu[2][0].u[j]);
      float o  = bf2f(gu[3][0].u[j]);
      float cn = f * cA[j] + cd * iv;
      float e  = __expf(2.0f * cd);
      float th = (e - 1.0f) / (e + 1.0f);
      H0[j] = o * th;                  // faithful double-tanh
      C0[j] = cn;
    }
#pragma unroll
    for (int j = 0; j < 8; ++j) {
      float f  = bf2f(gu[0][1].u[j]);
      float iv = bf2f(gu[1][1].u[j]);
      float cd = bf2f(gu[2][1].u[j]);
      float o  = bf2f(gu[3][1].u[j]);
      float cn = f * cB[j] + cd * iv;
      float e  = __expf(2.0f * cd);
      float th = (e - 1.0f) / (e + 1.0f);
      H1[j] = o * th;
      C1[j] = cn;
    }
    *(f32x8*)(La.h + base)     = H0;
    *(f32x8*)(La.h + base + 8) = H1;
    *(f32x8*)(La.c + base)     = C0;
    *(f32x8*)(La.c + base + 8) = C1;
    *(uint4*)(La.hb + base)     = cvt8(H0);
    *(uint4*)(La.hb + base + 8) = cvt8(H1);
  }
}

// ---- 128x128 m97-structure kernel (unchanged, round-0 verified): heads ----
__global__ __launch_bounds__(256, 2) void gemm_bt(
    const u16* __restrict__ A0, const u16* __restrict__ A1, int KA0, int K,
    SegArgs segs, int tileShift, int ldOut)
{
  __shared__ u16 As[BM * BK];
  __shared__ u16 Bs[BN * BK];

  const int tid  = threadIdx.x;
  const int lane = tid & 63;
  const int wave = tid >> 6;
  const int mBlock = blockIdx.x * BM;
  const int seg   = blockIdx.y >> tileShift;
  const int nTile = blockIdx.y & ((1 << tileShift) - 1);

  const u16* Wp = segs.W[seg];
  const int wm = wave & 1, wn = wave >> 1;

  const f32x4 zero = {0.f, 0.f, 0.f, 0.f};
  f32x4 acc[4][4];
#pragma unroll
  for (int i = 0; i < 4; ++i)
#pragma unroll
    for (int j = 0; j < 4; ++j) acc[i][j] = zero;

  for (int kb = 0; kb < K; kb += BK) {
    const u16* Aseg; int ka; int ldA;
    if (kb < KA0) { Aseg = A0; ka = kb;       ldA = KA0; }
    else          { Aseg = A1; ka = kb - KA0; ldA = K - KA0; }

#pragma unroll
    for (int it = 0; it < 4; ++it) {
      int s = it * 256 + tid;
      int m = s >> 3;
      int p = s & 7;
      int kc = p ^ (m & 7);
      const u16* srcA = Aseg + (size_t)(mBlock + m) * (size_t)ldA + (ka + kc * 8);
      const u16* srcB = Wp + (size_t)(nTile * BN + m) * (size_t)K + (kb + kc * 8);
      u16* dA = &As[(it * 256 + wave * 64) * 8];
      u16* dB = &Bs[(it * 256 + wave * 64) * 8];
      __builtin_amdgcn_global_load_lds((void*)srcA, (void*)dA, 16, 0, 0);
      __builtin_amdgcn_global_load_lds((void*)srcB, (void*)dB, 16, 0, 0);
    }
    __syncthreads();

#pragma unroll
    for (int ko = 0; ko < 2; ++ko) {
      bf16x8 af[4], bfr[4];
      int kcb = ko * 4 + (lane >> 4);
      int p = kcb ^ (lane & 7);
#pragma unroll
      for (int t = 0; t < 4; ++t) {
        int ml = wm * 64 + t * 16 + (lane & 15);
        af[t]  = *(const bf16x8*)&As[(ml * 8 + p) * 8];
        int nl = wn * 64 + t * 16 + (lane & 15);
        bfr[t] = *(const bf16x8*)&Bs[(nl * 8 + p) * 8];
      }
#pragma unroll
      for (int tm = 0; tm < 4; ++tm)
#pragma unroll
        for (int tn = 0; tn < 4; ++tn)
          acc[tm][tn] = __builtin_amdgcn_mfma_f32_16x16x32_bf16(af[tm], bfr[tn], acc[tm][tn], 0, 0, 0);
    }
    __syncthreads();
  }

  const float* bp = segs.b[seg];
  const int act = segs.act[seg];
  const int isBf = segs.bf16out[seg];
  u16*   opb = (u16*)segs.out[seg];
  float* opf = (float*)segs.out[seg];
  const int q  = lane >> 4;
  const int cl = lane & 15;
#pragma unroll
  for (int tn = 0; tn < 4; ++tn) {
    int col = nTile * BN + wn * 64 + tn * 16 + cl;
    float bv = bp[col];
#pragma unroll
    for (int tm = 0; tm < 4; ++tm) {
      int row = mBlock + wm * 64 + tm * 16 + q * 4;
#pragma unroll
      for (int r = 0; r < 4; ++r) {
        float v = actf(acc[tm][tn][r] + bv, act);
        size_t idx = (size_t)(row + r) * (size_t)ldOut + col;
        if (isBf) opb[idx] = f2bf(v); else opf[idx] = v;
      }
    }
  }
}

extern "C" void kernel_launch(void* const* d_in, const int* in_sizes, int n_in,
                              void* d_out, int out_size, void* d_ws, size_t ws_size,
                              hipStream_t stream)
{
  const size_t P   = 4096ull * 1024ull;  // 4,194,304 elements
  const size_t C2M = 2097152ull;         // region = 2M elements

  const float* X   = (const float*)d_in[0];
  const float* h1i = (const float*)d_in[1];
  const float* h2i = (const float*)d_in[2];
  const float* c1i = (const float*)d_in[3];
  const float* c2i = (const float*)d_in[4];
  const float* Wf1 = (const float*)d_in[5];  const float* bf1_ = (const float*)d_in[6];
  const float* Wi1 = (const float*)d_in[7];  const float* bi1_ = (const float*)d_in[8];
  const float* Wc1 = (const float*)d_in[9];  const float* bc1_ = (const float*)d_in[10];
  const float* Wo1 = (const float*)d_in[11]; const float* bo1_ = (const float*)d_in[12];
  const float* Wf2 = (const float*)d_in[13]; const float* bf2_ = (const float*)d_in[14];
  const float* Wi2 = (const float*)d_in[15]; const float* bi2_ = (const float*)d_in[16];
  const float* Wc2 = (const float*)d_in[17]; const float* bc2_ = (const float*)d_in[18];
  const float* Wo2 = (const float*)d_in[19]; const float* bo2_ = (const float*)d_in[20];
  const float* W3  = (const float*)d_in[21]; const float* b3_  = (const float*)d_in[22];
  const float* W4  = (const float*)d_in[23]; const float* b4_  = (const float*)d_in[24];

  float* out = (float*)d_out;     // fp32 outputs (reference dtype)
  float* h1  = out + P;
  float* h2  = out + 2 * P;
  float* c1  = out + 3 * P;
  float* c2  = out + 4 * P;

  // ws layout (80 MB), non-aliased during layer 1 (staggered cvt targets):
  //  W1b  @  0MB (16)      W2b  @ 16MB (16)
  //  W3b  @ 32MB ( 4)      W4b  @ 36MB ( 4)
  //  Xb   @ 40MB ( 8)      h1ib @ 48MB ( 8)
  //  h2ib @ 56MB ( 8)
  //  h1b  @ 64MB ( 8)      h2b  @ 72MB ( 8)
  //  out3b@  0MB (16)      (reuses W1b region, dead after gemm1)
  char* ws = (char*)d_ws;
  u16* W1b  = (u16*)ws;
  u16* W2b  = (u16*)(ws + (16ull << 20));
  u16* W3b  = (u16*)(ws + (32ull << 20));
  u16* W4b  = (u16*)(ws + (36ull << 20));
  u16* Xb   = (u16*)(ws + (40ull << 20));
  u16* h1ib = (u16*)(ws + (48ull << 20));
  u16* h2ib = (u16*)(ws + (56ull << 20));
  u16* h1b  = (u16*)(ws + (64ull << 20));
  u16* h2b  = (u16*)(ws + (72ull << 20));
  u16* out3b = W1b;

  dim3 blk(256, 1, 1);

  // ---- cvtA: only gemm1's direct inputs (W1 gates, X, h1i) ----
  CvtArgs ca;
  ca.src[0]=Wf1;        ca.dst[0]=W1b;
  ca.src[1]=Wi1;        ca.dst[1]=W1b + C2M;
  ca.src[2]=Wc1;        ca.dst[2]=W1b + 2*C2M;
  ca.src[3]=Wo1;        ca.dst[3]=W1b + 3*C2M;
  ca.src[4]=X;          ca.dst[4]=Xb;
  ca.src[5]=X + C2M;    ca.dst[5]=Xb + C2M;
  ca.src[6]=h1i;        ca.dst[6]=h1ib;
  ca.src[7]=h1i + C2M;  ca.dst[7]=h1ib + C2M;
  ca.src[8]=nullptr;    ca.dst[8]=nullptr;
  ca.src[9]=nullptr;    ca.dst[9]=nullptr;
  cvt_f2b<<<dim3(1024, 8, 1), blk, 0, stream>>>(ca);

  // ---- LSTM layer 1 + staggered cvt (W2 gates, h2i, W3, W4) ----
  LstmArgs l1;
  l1.W[0]=W1b; l1.W[1]=W1b+C2M; l1.W[2]=W1b+2*C2M; l1.W[3]=W1b+3*C2M;
  l1.b[0]=bf1_; l1.b[1]=bi1_; l1.b[2]=bc1_; l1.b[3]=bo1_;
  l1.cold=c1i; l1.h=h1; l1.c=c1; l1.hb=h1b;
  CvtW cw1;
  cw1.src[0]=Wf2;       cw1.dst[0]=W2b;
  cw1.src[1]=Wi2;       cw1.dst[1]=W2b + C2M;
  cw1.src[2]=Wc2;       cw1.dst[2]=W2b + 2*C2M;
  cw1.src[3]=Wo2;       cw1.dst[3]=W2b + 3*C2M;
  cw1.src[4]=h2i;       cw1.dst[4]=h2ib;
  cw1.src[5]=h2i + C2M; cw1.dst[5]=h2ib + C2M;
  cw1.src[6]=W3;        cw1.dst[6]=W3b;
  cw1.src[7]=W4;        cw1.dst[7]=W4b;
  cw1.n = 8;
  gemm_lstm2<<<dim3(32, 32, 1), blk, 0, stream>>>(Xb, h1ib, 1024, 2048, l1, cw1);

  // ---- LSTM layer 2: A = [h1b | h2ib] ----
  LstmArgs l2;
  l2.W[0]=W2b; l2.W[1]=W2b+C2M; l2.W[2]=W2b+2*C2M; l2.W[3]=W2b+3*C2M;
  l2.b[0]=bf2_; l2.b[1]=bi2_; l2.b[2]=bc2_; l2.b[3]=bo2_;
  l2.cold=c2i; l2.h=h2; l2.c=c2; l2.hb=h2b;
  CvtW cw0; cw0.n = 0;
  for (int i = 0; i < 8; ++i) { cw0.src[i]=nullptr; cw0.dst[i]=nullptr; }
  gemm_lstm2<<<dim3(32, 32, 1), blk, 0, stream>>>(h1b, h2ib, 1024, 2048, l2, cw0);

  // ---- head: out3b = relu(h2b @ W3^T + b3), N=2048, K=1024, bf16 out ----
  SegArgs s3;
  for (int g = 0; g < 4; ++g) { s3.W[g]=W3b; s3.b[g]=b3_; s3.out[g]=out3b; s3.act[g]=3; s3.bf16out[g]=1; }
  gemm_bt<<<dim3(32,16,1), blk, 0, stream>>>(h2b, (const u16*)nullptr, 1024, 1024, s3, 4, 2048);

  // ---- head: out = out3b @ W4^T + b4, N=1024, K=2048, fp32 out ----
  SegArgs s4;
  for (int g = 0; g < 4; ++g) { s4.W[g]=W4b; s4.b[g]=b4_; s4.out[g]=out; s4.act[g]=0; s4.bf16out[g]=0; }
  gemm_bt<<<dim3(32,8,1), blk, 0, stream>>>(out3b, (const u16*)nullptr, 2048, 2048, s4, 3, 1024);
}